// Round 1
// baseline (246.331 us; speedup 1.0000x reference)
//
#include <hip/hip_runtime.h>
#include <stdint.h>

typedef __bf16 bf16x8 __attribute__((ext_vector_type(8)));
typedef float f32x4 __attribute__((ext_vector_type(4)));
typedef uint16_t u16;
typedef uint32_t u32;
typedef uint32_t gu32 __attribute__((address_space(1)));
typedef uint32_t lu32 __attribute__((address_space(3)));

#define DEV static __device__ __forceinline__

DEV u16 f2bf(float f) {
  u32 u = __builtin_bit_cast(u32, f);
  return (u16)((u + 0x8000u) >> 16);
}

DEV void gload16(const void* g, void* l) {
  __builtin_amdgcn_global_load_lds((gu32*)(uintptr_t)g, (lu32*)(uintptr_t)l,
                                   16, 0, 0);
}

// ============ 1) fp32 -> bf16 convert (x, qkv_w, proj_w) ============
__global__ __launch_bounds__(256) void convert_k(
    const float* __restrict__ x, const float* __restrict__ wq,
    const float* __restrict__ wp, u16* __restrict__ xb, u16* __restrict__ wqb,
    u16* __restrict__ wpb) {
  const int NX = 1048576, NQ = 786432, NP = 262144;  // float4 counts
  const int tot = NX + NQ + NP;
  int idx = blockIdx.x * blockDim.x + threadIdx.x;
  int stride = gridDim.x * blockDim.x;
  for (; idx < tot; idx += stride) {
    int i = idx;
    const float* s;
    u16* d;
    if (i < NX) {
      s = x; d = xb;
    } else if (i < NX + NQ) {
      i -= NX; s = wq; d = wqb;
    } else {
      i -= NX + NQ; s = wp; d = wpb;
    }
    float4 v = ((const float4*)s)[i];
    ushort4 o;
    o.x = f2bf(v.x); o.y = f2bf(v.y); o.z = f2bf(v.z); o.w = f2bf(v.w);
    ((ushort4*)d)[i] = o;
  }
}

// ============ 2/4) C = A[M,K] * B[N,K]^T, 128x128 tile, 4 waves ============
// EPI 0: qkv epilogue (q scaled+scattered, k scattered, v transposed [B,H,D,N])
// EPI 1: proj epilogue (fp32 out + bias)
template <int EPI>
__global__ __launch_bounds__(256) void gemm_bt(
    const u16* __restrict__ A, const u16* __restrict__ B, int K,
    u16* __restrict__ qbuf, u16* __restrict__ kbuf, u16* __restrict__ vtbuf,
    float* __restrict__ outp, const float* __restrict__ bias) {
  constexpr int TRN = (EPI == 0) ? 128 * 136 : 8192;
  __shared__ union alignas(16) SM {
    u16 ab[8192];       // A tile [128][32] + B tile [128][32]
    u16 tr[TRN];        // v-transpose buffer, stride 136 (16B-aligned rows)
  } sm;
  const int tid = threadIdx.x;
  const int l = tid & 63, w = tid >> 6, g = l >> 4, r = l & 15;
  const int bm = blockIdx.x, bn = blockIdx.y;
  const int wr = w >> 1, wc = w & 1;
  f32x4 acc[4][4] = {};
  const u16* Ab = A + (size_t)bm * 128 * K;
  const u16* Bb = B + (size_t)bn * 128 * K;
  char* sA = (char*)sm.ab;
  char* sB = sA + 8192;
  const int kit = K >> 5;
  for (int kt = 0; kt < kit; ++kt) {
    const int k0 = kt << 5;
#pragma unroll
    for (int i = 0; i < 2; ++i) {
      int c = i * 256 + tid;
      int row = c >> 2, sl = c & 3;
      gload16(Ab + row * K + k0 + sl * 8, sA + (i * 256 + w * 64) * 16);
      gload16(Bb + row * K + k0 + sl * 8, sB + (i * 256 + w * 64) * 16);
    }
    __syncthreads();
    bf16x8 af[4], bf[4];
#pragma unroll
    for (int mb = 0; mb < 4; ++mb)
      af[mb] = *(const bf16x8*)(sA + (wr * 64 + mb * 16 + r) * 64 + g * 16);
#pragma unroll
    for (int nb = 0; nb < 4; ++nb)
      bf[nb] = *(const bf16x8*)(sB + (wc * 64 + nb * 16 + r) * 64 + g * 16);
#pragma unroll
    for (int mb = 0; mb < 4; ++mb)
#pragma unroll
      for (int nb = 0; nb < 4; ++nb)
        acc[mb][nb] = __builtin_amdgcn_mfma_f32_16x16x32_bf16(
            af[mb], bf[nb], acc[mb][nb], 0, 0, 0);
    __syncthreads();
  }
  const int m0 = bm * 128 + wr * 64;
  if (EPI == 1) {
#pragma unroll
    for (int nb = 0; nb < 4; ++nb) {
      int o = bn * 128 + wc * 64 + nb * 16 + r;
      float bi = bias[o];
#pragma unroll
      for (int mb = 0; mb < 4; ++mb)
#pragma unroll
        for (int j = 0; j < 4; ++j) {
          int m = m0 + mb * 16 + g * 4 + j;
          outp[(size_t)m * 1024 + o] = acc[mb][nb][j] + bi;
        }
    }
  } else {
    const int o0 = bn * 128;
    if (o0 < 2048) {
      // q (o<1024) or k: direct scatter to [B,H,N,D]
      u16* dst = (o0 < 1024) ? qbuf : kbuf;
      // fold softmax scale D^-0.5 * log2(e) into q so attention uses exp2
      const float qs = (o0 < 1024) ? 0.18033688011112042f : 1.0f;
#pragma unroll
      for (int nb = 0; nb < 4; ++nb) {
        int o = o0 + wc * 64 + nb * 16 + r;
        int h = (o >> 6) & 15, d = o & 63;
#pragma unroll
        for (int mb = 0; mb < 4; ++mb)
#pragma unroll
          for (int j = 0; j < 4; ++j) {
            int m = m0 + mb * 16 + g * 4 + j;
            int b = m >> 11, n = m & 2047;
            dst[(size_t)(((b << 4) + h) * 2048 + n) * 64 + d] =
                f2bf(acc[mb][nb][j] * qs);
          }
      }
    } else {
      // v block: transpose 128(m) x 128(o) tile via LDS, write [B,H,D,N]
#pragma unroll
      for (int nb = 0; nb < 4; ++nb) {
        int ol = wc * 64 + nb * 16 + r;
#pragma unroll
        for (int mb = 0; mb < 4; ++mb)
#pragma unroll
          for (int j = 0; j < 4; ++j) {
            int ml = wr * 64 + mb * 16 + g * 4 + j;
            sm.tr[ol * 136 + ml] = f2bf(acc[mb][nb][j]);
          }
      }
      __syncthreads();
      const int b = bm >> 4;
      const int n0 = (bm & 15) * 128;
#pragma unroll
      for (int i = 0; i < 8; ++i) {
        int c = i * 256 + tid;
        int ro = c >> 4, ms = c & 15;
        int o = o0 + ro;
        int h = (o >> 6) & 15, d = o & 63;
        bf16x8 v = *(const bf16x8*)(sm.tr + ro * 136 + ms * 8);
        *(bf16x8*)(vtbuf + (size_t)(((b << 4) + h) * 64 + d) * 2048 + n0 +
                   ms * 8) = v;
      }
    }
  }
}

// ============ 3) flash attention: per (b,h), 128 q-rows per block ============
// K LDS tile [64 k][64 d], Vt LDS tile [64 d][64 k]; both XOR-swizzled
// ((row&7)<<4 on byte addr) via pre-swizzled global_load_lds source.
__global__ __launch_bounds__(256) void attn_k(
    const u16* __restrict__ qbuf, const u16* __restrict__ kbuf,
    const u16* __restrict__ vtbuf, u16* __restrict__ hbuf) {
  __shared__ alignas(16) char sK[8192];
  __shared__ alignas(16) char sV[8192];
  __shared__ alignas(16) char sP[4][4096];
  const int tid = threadIdx.x;
  const int l = tid & 63, w = tid >> 6, g = l >> 4, r = l & 15;
  const int bh = blockIdx.y;  // b*16+h
  const int q0 = blockIdx.x * 128 + w * 32;
  const u16* Qb = qbuf + ((size_t)bh * 2048 + q0) * 64;
  bf16x8 qf[2][2];
#pragma unroll
  for (int qh = 0; qh < 2; ++qh)
#pragma unroll
    for (int ds = 0; ds < 2; ++ds)
      qf[qh][ds] = *(const bf16x8*)(Qb + (qh * 16 + r) * 64 + ds * 32 + g * 8);
  f32x4 acc[2][4] = {};
  float mrun[2][4], lrun[2][4];
#pragma unroll
  for (int qh = 0; qh < 2; ++qh)
#pragma unroll
    for (int j = 0; j < 4; ++j) {
      mrun[qh][j] = -1e30f;
      lrun[qh][j] = 0.f;
    }
  const u16* Kb = kbuf + (size_t)bh * 2048 * 64;
  const u16* Vb = vtbuf + (size_t)bh * 64 * 2048;
  char* pw = sP[w];
  for (int t = 0; t < 32; ++t) {
    const int k0 = t * 64;
#pragma unroll
    for (int i = 0; i < 2; ++i) {
      int c = i * 256 + tid;
      int row = c >> 3, sl = c & 7;
      gload16(Kb + (k0 + row) * 64 + ((sl ^ (row & 7)) * 8),
              sK + (i * 256 + w * 64) * 16);
      gload16(Vb + (size_t)row * 2048 + k0 + ((sl ^ (row & 7)) * 8),
              sV + (i * 256 + w * 64) * 16);
    }
    __syncthreads();
    // S = Q K^T  (S row=q=g*4+j, col=k=r within each 16x16 tile)
    bf16x8 kf[4][2];
#pragma unroll
    for (int kb = 0; kb < 4; ++kb)
#pragma unroll
      for (int ds = 0; ds < 2; ++ds) {
        int row = kb * 16 + r;
        kf[kb][ds] = *(const bf16x8*)(sK + row * 128 +
                                      ((ds * 64 + g * 16) ^ ((row & 7) << 4)));
      }
    f32x4 s[2][4];
#pragma unroll
    for (int qh = 0; qh < 2; ++qh)
#pragma unroll
      for (int kb = 0; kb < 4; ++kb) {
        f32x4 z = {};
        z = __builtin_amdgcn_mfma_f32_16x16x32_bf16(qf[qh][0], kf[kb][0], z, 0, 0, 0);
        z = __builtin_amdgcn_mfma_f32_16x16x32_bf16(qf[qh][1], kf[kb][1], z, 0, 0, 0);
        s[qh][kb] = z;
      }
    // online softmax (rows live across lanes with same g; reduce over lane&15)
    float p[2][4][4];
#pragma unroll
    for (int qh = 0; qh < 2; ++qh)
#pragma unroll
      for (int j = 0; j < 4; ++j) {
        float mx = fmaxf(fmaxf(s[qh][0][j], s[qh][1][j]),
                         fmaxf(s[qh][2][j], s[qh][3][j]));
        mx = fmaxf(mx, __shfl_xor(mx, 1));
        mx = fmaxf(mx, __shfl_xor(mx, 2));
        mx = fmaxf(mx, __shfl_xor(mx, 4));
        mx = fmaxf(mx, __shfl_xor(mx, 8));
        float mn = fmaxf(mrun[qh][j], mx);
        float corr = exp2f(mrun[qh][j] - mn);
        float ps = 0.f;
#pragma unroll
        for (int kb = 0; kb < 4; ++kb) {
          float e = exp2f(s[qh][kb][j] - mn);
          p[qh][kb][j] = e;
          ps += e;
        }
        ps += __shfl_xor(ps, 1);
        ps += __shfl_xor(ps, 2);
        ps += __shfl_xor(ps, 4);
        ps += __shfl_xor(ps, 8);
        lrun[qh][j] = lrun[qh][j] * corr + ps;
        mrun[qh][j] = mn;
#pragma unroll
        for (int db = 0; db < 4; ++db) acc[qh][db][j] *= corr;
      }
    // P -> per-wave LDS (swizzled), then PV
#pragma unroll
    for (int qh = 0; qh < 2; ++qh)
#pragma unroll
      for (int kb = 0; kb < 4; ++kb)
#pragma unroll
        for (int j = 0; j < 4; ++j) {
          int qrow = qh * 16 + g * 4 + j;
          int kc = kb * 16 + r;
          *(u16*)(pw + qrow * 128 + ((kc * 2) ^ ((qrow & 7) << 4))) =
              f2bf(p[qh][kb][j]);
        }
    asm volatile("s_waitcnt lgkmcnt(0)" ::: "memory");
    bf16x8 pf[2][2], vf[2][4];
#pragma unroll
    for (int qh = 0; qh < 2; ++qh)
#pragma unroll
      for (int ks = 0; ks < 2; ++ks) {
        int qrow = qh * 16 + r;
        pf[qh][ks] = *(const bf16x8*)(pw + qrow * 128 + ((ks * 64 + g * 16) ^
                                                         ((qrow & 7) << 4)));
      }
#pragma unroll
    for (int ks = 0; ks < 2; ++ks)
#pragma unroll
      for (int db = 0; db < 4; ++db) {
        int drow = db * 16 + r;
        vf[ks][db] = *(const bf16x8*)(sV + drow * 128 + ((ks * 64 + g * 16) ^
                                                         ((drow & 7) << 4)));
      }
#pragma unroll
    for (int qh = 0; qh < 2; ++qh)
#pragma unroll
      for (int db = 0; db < 4; ++db) {
        acc[qh][db] = __builtin_amdgcn_mfma_f32_16x16x32_bf16(
            pf[qh][0], vf[0][db], acc[qh][db], 0, 0, 0);
        acc[qh][db] = __builtin_amdgcn_mfma_f32_16x16x32_bf16(
            pf[qh][1], vf[1][db], acc[qh][db], 0, 0, 0);
      }
    __syncthreads();
  }
  const int b = bh >> 4, h = bh & 15;
#pragma unroll
  for (int qh = 0; qh < 2; ++qh)
#pragma unroll
    for (int j = 0; j < 4; ++j) {
      float inv = 1.0f / lrun[qh][j];
      int q = q0 + qh * 16 + g * 4 + j;
#pragma unroll
      for (int db = 0; db < 4; ++db) {
        int d = db * 16 + r;
        hbuf[((size_t)(b * 2048 + q)) * 1024 + h * 64 + d] =
            f2bf(acc[qh][db][j] * inv);
      }
    }
}

extern "C" void kernel_launch(void* const* d_in, const int* in_sizes, int n_in,
                              void* d_out, int out_size, void* d_ws,
                              size_t ws_size, hipStream_t stream) {
  const float* x = (const float*)d_in[0];
  const float* qkv_w = (const float*)d_in[1];
  const float* proj_w = (const float*)d_in[2];
  const float* proj_b = (const float*)d_in[3];
  float* out = (float*)d_out;
  char* ws = (char*)d_ws;
  if (ws_size < 50331648) return;  // need 48 MiB of scratch
  u16* xb  = (u16*)(ws + 0);         // [4096][1024] bf16
  u16* wqb = (u16*)(ws + 8388608);   // [3072][1024] bf16
  u16* wpb = (u16*)(ws + 14680064);  // [1024][1024] bf16
  u16* qb  = (u16*)(ws + 16777216);  // [B,H,N,D] bf16 (pre-scaled)
  u16* kb  = (u16*)(ws + 25165824);  // [B,H,N,D] bf16
  u16* vtb = (u16*)(ws + 33554432);  // [B,H,D,N] bf16
  u16* hb  = (u16*)(ws + 41943040);  // [B*N][C] bf16
  convert_k<<<dim3(2048), dim3(256), 0, stream>>>(x, qkv_w, proj_w, xb, wqb, wpb);
  gemm_bt<0><<<dim3(32, 24), dim3(256), 0, stream>>>(
      xb, wqb, 1024, qb, kb, vtb, nullptr, nullptr);
  attn_k<<<dim3(16, 32), dim3(256), 0, stream>>>(qb, kb, vtb, hb);
  gemm_bt<1><<<dim3(32, 8), dim3(256), 0, stream>>>(
      hb, wpb, 1024, nullptr, nullptr, nullptr, out, proj_b);
}

// Round 2
// 154.842 us; speedup vs baseline: 1.5908x; 1.5908x over previous
//
#include <hip/hip_runtime.h>
#include <stdint.h>

typedef __bf16 bf16x8 __attribute__((ext_vector_type(8)));
typedef float f32x4 __attribute__((ext_vector_type(4)));
typedef uint16_t u16;
typedef uint32_t u32;
typedef uint32_t gu32 __attribute__((address_space(1)));
typedef uint32_t lu32 __attribute__((address_space(3)));

#define DEV static __device__ __forceinline__

DEV u16 f2bf(float f) {
  u32 u = __builtin_bit_cast(u32, f);
  return (u16)((u + 0x8000u) >> 16);
}

DEV u32 pkbf(float a, float b) {
  u32 ua = __builtin_bit_cast(u32, a);
  u32 ub = __builtin_bit_cast(u32, b);
  return ((ua + 0x8000u) >> 16) | ((ub + 0x8000u) & 0xFFFF0000u);
}

DEV void gload16(const void* g, void* l) {
  __builtin_amdgcn_global_load_lds((gu32*)(uintptr_t)g, (lu32*)(uintptr_t)l,
                                   16, 0, 0);
}

// ============ 1) fp32 -> bf16 convert (x, qkv_w, proj_w) ============
__global__ __launch_bounds__(256) void convert_k(
    const float* __restrict__ x, const float* __restrict__ wq,
    const float* __restrict__ wp, u16* __restrict__ xb, u16* __restrict__ wqb,
    u16* __restrict__ wpb) {
  const int NX = 1048576, NQ = 786432, NP = 262144;  // float4 counts
  const int tot = NX + NQ + NP;
  int idx = blockIdx.x * blockDim.x + threadIdx.x;
  int stride = gridDim.x * blockDim.x;
  for (; idx < tot; idx += stride) {
    int i = idx;
    const float* s;
    u16* d;
    if (i < NX) {
      s = x; d = xb;
    } else if (i < NX + NQ) {
      i -= NX; s = wq; d = wqb;
    } else {
      i -= NX + NQ; s = wp; d = wpb;
    }
    float4 v = ((const float4*)s)[i];
    ushort4 o;
    o.x = f2bf(v.x); o.y = f2bf(v.y); o.z = f2bf(v.z); o.w = f2bf(v.w);
    ((ushort4*)d)[i] = o;
  }
}

// ============ 2/4) C = A[M,K] * B[N,K]^T, 128x128 tile, 4 waves ============
template <int EPI>
__global__ __launch_bounds__(256) void gemm_bt(
    const u16* __restrict__ A, const u16* __restrict__ B, int K,
    u16* __restrict__ qbuf, u16* __restrict__ kbuf, u16* __restrict__ vtbuf,
    float* __restrict__ outp, const float* __restrict__ bias) {
  constexpr int TRN = (EPI == 0) ? 128 * 136 : 8192;
  __shared__ union alignas(16) SM {
    u16 ab[8192];       // A tile [128][32] + B tile [128][32]
    u16 tr[TRN];        // v-transpose buffer, stride 136
  } sm;
  const int tid = threadIdx.x;
  const int l = tid & 63, w = tid >> 6, g = l >> 4, r = l & 15;
  const int bm = blockIdx.x, bn = blockIdx.y;
  const int wr = w >> 1, wc = w & 1;
  f32x4 acc[4][4] = {};
  const u16* Ab = A + (size_t)bm * 128 * K;
  const u16* Bb = B + (size_t)bn * 128 * K;
  char* sA = (char*)sm.ab;
  char* sB = sA + 8192;
  const int kit = K >> 5;
  for (int kt = 0; kt < kit; ++kt) {
    const int k0 = kt << 5;
#pragma unroll
    for (int i = 0; i < 2; ++i) {
      int c = i * 256 + tid;
      int row = c >> 2, sl = c & 3;
      gload16(Ab + row * K + k0 + sl * 8, sA + (i * 256 + w * 64) * 16);
      gload16(Bb + row * K + k0 + sl * 8, sB + (i * 256 + w * 64) * 16);
    }
    __syncthreads();
    bf16x8 af[4], bf[4];
#pragma unroll
    for (int mb = 0; mb < 4; ++mb)
      af[mb] = *(const bf16x8*)(sA + (wr * 64 + mb * 16 + r) * 64 + g * 16);
#pragma unroll
    for (int nb = 0; nb < 4; ++nb)
      bf[nb] = *(const bf16x8*)(sB + (wc * 64 + nb * 16 + r) * 64 + g * 16);
#pragma unroll
    for (int mb = 0; mb < 4; ++mb)
#pragma unroll
      for (int nb = 0; nb < 4; ++nb)
        acc[mb][nb] = __builtin_amdgcn_mfma_f32_16x16x32_bf16(
            af[mb], bf[nb], acc[mb][nb], 0, 0, 0);
    __syncthreads();
  }
  const int m0 = bm * 128 + wr * 64;
  if (EPI == 1) {
#pragma unroll
    for (int nb = 0; nb < 4; ++nb) {
      int o = bn * 128 + wc * 64 + nb * 16 + r;
      float bi = bias[o];
#pragma unroll
      for (int mb = 0; mb < 4; ++mb)
#pragma unroll
        for (int j = 0; j < 4; ++j) {
          int m = m0 + mb * 16 + g * 4 + j;
          outp[(size_t)m * 1024 + o] = acc[mb][nb][j] + bi;
        }
    }
  } else {
    const int o0 = bn * 128;
    if (o0 < 2048) {
      u16* dst = (o0 < 1024) ? qbuf : kbuf;
      const float qs = (o0 < 1024) ? 0.18033688011112042f : 1.0f;
#pragma unroll
      for (int nb = 0; nb < 4; ++nb) {
        int o = o0 + wc * 64 + nb * 16 + r;
        int h = (o >> 6) & 15, d = o & 63;
#pragma unroll
        for (int mb = 0; mb < 4; ++mb)
#pragma unroll
          for (int j = 0; j < 4; ++j) {
            int m = m0 + mb * 16 + g * 4 + j;
            int b = m >> 11, n = m & 2047;
            dst[(size_t)(((b << 4) + h) * 2048 + n) * 64 + d] =
                f2bf(acc[mb][nb][j] * qs);
          }
      }
    } else {
      // v block: transpose 128(m) x 128(o) tile via LDS, write [B,H,D,N]
#pragma unroll
      for (int nb = 0; nb < 4; ++nb) {
        int ol = wc * 64 + nb * 16 + r;
#pragma unroll
        for (int mb = 0; mb < 4; ++mb)
#pragma unroll
          for (int j = 0; j < 4; ++j) {
            int ml = wr * 64 + mb * 16 + g * 4 + j;
            sm.tr[ol * 136 + ml] = f2bf(acc[mb][nb][j]);
          }
      }
      __syncthreads();
      const int b = bm >> 4;
      const int n0 = (bm & 15) * 128;
#pragma unroll
      for (int i = 0; i < 8; ++i) {
        int c = i * 256 + tid;
        int ro = c >> 4, ms = c & 15;
        int o = o0 + ro;
        int h = (o >> 6) & 15, d = o & 63;
        bf16x8 v = *(const bf16x8*)(sm.tr + ro * 136 + ms * 8);
        *(bf16x8*)(vtbuf + (size_t)(((b << 4) + h) * 64 + d) * 2048 + n0 +
                   ms * 8) = v;
      }
    }
  }
}

// ============ 3) flash attention, swapped-operand in-register softmax ======
// Each block: 4 waves x 32 q-rows = 128 q. K/V tiles (64x64) double-buffered
// in LDS, XOR-swizzled ((row&7)<<4) via pre-swizzled global source.
// S^T = mfma(K, Q): lane holds column q=lane&15, rows k=kb*16+g*4+j.
// Softmax per q: serial max/sum over 16 regs + 2 shfl_xor across g-groups.
// O^T = mfma(Vt, Pt) accumulated per (d-row, q-col).
__global__ __launch_bounds__(256) void attn_k(
    const u16* __restrict__ qbuf, const u16* __restrict__ kbuf,
    const u16* __restrict__ vtbuf, u16* __restrict__ hbuf) {
  __shared__ alignas(16) char sK[2][8192];
  __shared__ alignas(16) char sV[2][8192];
  __shared__ alignas(16) char sP[4][4096];
  const int tid = threadIdx.x;
  const int l = tid & 63, w = tid >> 6, g = l >> 4, r = l & 15;
  // XCD-grouped swizzle: 16 q-blocks of one bh land on one XCD's L2
  const int id = blockIdx.x;
  const int swz = (id & 7) * 64 + (id >> 3);
  const int bh = swz >> 4;
  const int q0 = (swz & 15) * 128 + w * 32;
  const u16* Qb = qbuf + ((size_t)bh * 2048 + q0) * 64;
  const u16* Kb = kbuf + (size_t)bh * 2048 * 64;
  const u16* Vb = vtbuf + (size_t)bh * 64 * 2048;
  char* pw = sP[w];
  // Q fragments (B-operand: col q=r, contraction d = ds*32 + g*8..+7)
  bf16x8 qf[2][2];
#pragma unroll
  for (int qh = 0; qh < 2; ++qh)
#pragma unroll
    for (int ds = 0; ds < 2; ++ds)
      qf[qh][ds] = *(const bf16x8*)(Qb + (qh * 16 + r) * 64 + ds * 32 + g * 8);
  f32x4 acc[2][4] = {};
  float mrun[2] = {-1e30f, -1e30f}, lrun[2] = {0.f, 0.f};

  auto stage = [&](int buf, int t) {
    const int k0 = t * 64;
#pragma unroll
    for (int i = 0; i < 2; ++i) {
      int c = i * 256 + tid;
      int row = c >> 3, sl = c & 7;
      gload16(Kb + (k0 + row) * 64 + ((sl ^ (row & 7)) * 8),
              sK[buf] + (i * 256 + w * 64) * 16);
      gload16(Vb + (size_t)row * 2048 + k0 + ((sl ^ (row & 7)) * 8),
              sV[buf] + (i * 256 + w * 64) * 16);
    }
  };

  stage(0, 0);
  __syncthreads();
  int cur = 0;
  for (int t = 0; t < 32; ++t) {
    if (t < 31) stage(cur ^ 1, t + 1);
    // K fragments (A-operand: row k = kb*16+r, contraction d)
    bf16x8 kf[4][2];
#pragma unroll
    for (int kb = 0; kb < 4; ++kb)
#pragma unroll
      for (int ds = 0; ds < 2; ++ds) {
        int row = kb * 16 + r;
        kf[kb][ds] = *(const bf16x8*)(sK[cur] + row * 128 +
                                      ((ds * 64 + g * 16) ^ ((row & 7) << 4)));
      }
    // S^T = K * Q^T
    f32x4 st[2][4];
    __builtin_amdgcn_s_setprio(1);
#pragma unroll
    for (int qh = 0; qh < 2; ++qh)
#pragma unroll
      for (int kb = 0; kb < 4; ++kb) {
        f32x4 z = {};
        z = __builtin_amdgcn_mfma_f32_16x16x32_bf16(kf[kb][0], qf[qh][0], z, 0, 0, 0);
        z = __builtin_amdgcn_mfma_f32_16x16x32_bf16(kf[kb][1], qf[qh][1], z, 0, 0, 0);
        st[qh][kb] = z;
      }
    __builtin_amdgcn_s_setprio(0);
    // V^T fragments (A-operand: row d = db*16+r, contraction k)
    bf16x8 vf[2][4];
#pragma unroll
    for (int ks = 0; ks < 2; ++ks)
#pragma unroll
      for (int db = 0; db < 4; ++db) {
        int drow = db * 16 + r;
        vf[ks][db] = *(const bf16x8*)(sV[cur] + drow * 128 +
                                      ((ks * 64 + g * 16) ^ ((drow & 7) << 4)));
      }
    // in-register online softmax (per lane: q-column r, 16 k-values per qh)
#pragma unroll
    for (int qh = 0; qh < 2; ++qh) {
      float mx = fmaxf(fmaxf(st[qh][0][0], st[qh][0][1]),
                       fmaxf(st[qh][0][2], st[qh][0][3]));
#pragma unroll
      for (int kb = 1; kb < 4; ++kb)
#pragma unroll
        for (int j = 0; j < 4; ++j) mx = fmaxf(mx, st[qh][kb][j]);
      mx = fmaxf(mx, __shfl_xor(mx, 16));
      mx = fmaxf(mx, __shfl_xor(mx, 32));
      if (__any(mx > mrun[qh] + 8.0f)) {  // defer-rescale, THR=8 (exp2 units)
        float mn = fmaxf(mrun[qh], mx);
        float corr = exp2f(mrun[qh] - mn);
        lrun[qh] *= corr;
#pragma unroll
        for (int db = 0; db < 4; ++db)
#pragma unroll
          for (int j = 0; j < 4; ++j) acc[qh][db][j] *= corr;
        mrun[qh] = mn;
      }
      float ps = 0.f;
#pragma unroll
      for (int kb = 0; kb < 4; ++kb)
#pragma unroll
        for (int j = 0; j < 4; ++j) {
          float e = exp2f(st[qh][kb][j] - mrun[qh]);
          st[qh][kb][j] = e;
          ps += e;
        }
      ps += __shfl_xor(ps, 16);
      ps += __shfl_xor(ps, 32);
      lrun[qh] += ps;
    }
    // P^T -> per-wave LDS as [q][k], packed b64 writes, swizzled rows
#pragma unroll
    for (int qh = 0; qh < 2; ++qh) {
      int q2 = qh * 16 + r;
      int sw = (q2 & 7) << 4;
#pragma unroll
      for (int kb = 0; kb < 4; ++kb) {
        uint2 pk;
        pk.x = pkbf(st[qh][kb][0], st[qh][kb][1]);
        pk.y = pkbf(st[qh][kb][2], st[qh][kb][3]);
        *(uint2*)(pw + q2 * 128 + ((kb * 32 + g * 8) ^ sw)) = pk;
      }
    }
    asm volatile("s_waitcnt lgkmcnt(0)" ::: "memory");
    // P^T fragments (B-operand: col q = r, contraction k = ks*32+g*8..+7)
    bf16x8 pf[2][2];
#pragma unroll
    for (int qh = 0; qh < 2; ++qh) {
      int q2 = qh * 16 + r;
#pragma unroll
      for (int ks = 0; ks < 2; ++ks)
        pf[qh][ks] = *(const bf16x8*)(pw + q2 * 128 +
                                      ((ks * 64 + g * 16) ^ ((q2 & 7) << 4)));
    }
    // O^T += V^T * P^T
    __builtin_amdgcn_s_setprio(1);
#pragma unroll
    for (int qh = 0; qh < 2; ++qh)
#pragma unroll
      for (int db = 0; db < 4; ++db) {
        acc[qh][db] = __builtin_amdgcn_mfma_f32_16x16x32_bf16(
            vf[0][db], pf[qh][0], acc[qh][db], 0, 0, 0);
        acc[qh][db] = __builtin_amdgcn_mfma_f32_16x16x32_bf16(
            vf[1][db], pf[qh][1], acc[qh][db], 0, 0, 0);
      }
    __builtin_amdgcn_s_setprio(0);
    __syncthreads();
    cur ^= 1;
  }
  // epilogue: O^T lane holds d=db*16+g*4+j (rows), q=r (col)
  const int b = bh >> 4, h = bh & 15;
#pragma unroll
  for (int qh = 0; qh < 2; ++qh) {
    float inv = 1.0f / lrun[qh];
    int q = q0 + qh * 16 + r;
#pragma unroll
    for (int db = 0; db < 4; ++db) {
      uint2 pk;
      pk.x = pkbf(acc[qh][db][0] * inv, acc[qh][db][1] * inv);
      pk.y = pkbf(acc[qh][db][2] * inv, acc[qh][db][3] * inv);
      *(uint2*)(hbuf + ((size_t)(b * 2048 + q)) * 1024 + h * 64 + db * 16 +
                g * 4) = pk;
    }
  }
}

extern "C" void kernel_launch(void* const* d_in, const int* in_sizes, int n_in,
                              void* d_out, int out_size, void* d_ws,
                              size_t ws_size, hipStream_t stream) {
  const float* x = (const float*)d_in[0];
  const float* qkv_w = (const float*)d_in[1];
  const float* proj_w = (const float*)d_in[2];
  const float* proj_b = (const float*)d_in[3];
  float* out = (float*)d_out;
  char* ws = (char*)d_ws;
  if (ws_size < 50331648) return;  // need 48 MiB of scratch
  u16* xb  = (u16*)(ws + 0);         // [4096][1024] bf16
  u16* wqb = (u16*)(ws + 8388608);   // [3072][1024] bf16
  u16* wpb = (u16*)(ws + 14680064);  // [1024][1024] bf16
  u16* qb  = (u16*)(ws + 16777216);  // [B,H,N,D] bf16 (pre-scaled)
  u16* kb  = (u16*)(ws + 25165824);  // [B,H,N,D] bf16
  u16* vtb = (u16*)(ws + 33554432);  // [B,H,D,N] bf16
  u16* hb  = (u16*)(ws + 41943040);  // [B*N][C] bf16
  convert_k<<<dim3(2048), dim3(256), 0, stream>>>(x, qkv_w, proj_w, xb, wqb, wpb);
  gemm_bt<0><<<dim3(32, 24), dim3(256), 0, stream>>>(
      xb, wqb, 1024, qb, kb, vtb, nullptr, nullptr);
  attn_k<<<dim3(512), dim3(256), 0, stream>>>(qb, kb, vtb, hb);
  gemm_bt<1><<<dim3(32, 8), dim3(256), 0, stream>>>(
      hb, wpb, 1024, nullptr, nullptr, nullptr, out, proj_b);
}

// Round 5
// 146.849 us; speedup vs baseline: 1.6774x; 1.0544x over previous
//
#include <hip/hip_runtime.h>
#include <stdint.h>

typedef __bf16 bf16x8 __attribute__((ext_vector_type(8)));
typedef float f32x4 __attribute__((ext_vector_type(4)));
typedef float f32x16 __attribute__((ext_vector_type(16)));
typedef uint16_t u16;
typedef uint32_t u32;
typedef uint32_t gu32 __attribute__((address_space(1)));
typedef uint32_t lu32 __attribute__((address_space(3)));

#define DEV static __device__ __forceinline__

DEV u16 f2bf(float f) {
  u32 u = __builtin_bit_cast(u32, f);
  return (u16)((u + 0x8000u) >> 16);
}

DEV u32 cvtpk(float lo, float hi) {
  u32 r;
  asm("v_cvt_pk_bf16_f32 %0, %1, %2" : "=v"(r) : "v"(lo), "v"(hi));
  return r;
}

DEV void gload16(const void* g, void* l) {
  __builtin_amdgcn_global_load_lds((gu32*)(uintptr_t)g, (lu32*)(uintptr_t)l,
                                   16, 0, 0);
}

DEV float tmax16(f32x16 v) {
  float a = fmaxf(fmaxf(v[0], v[1]), fmaxf(v[2], v[3]));
  float b = fmaxf(fmaxf(v[4], v[5]), fmaxf(v[6], v[7]));
  float c = fmaxf(fmaxf(v[8], v[9]), fmaxf(v[10], v[11]));
  float d = fmaxf(fmaxf(v[12], v[13]), fmaxf(v[14], v[15]));
  return fmaxf(fmaxf(a, b), fmaxf(c, d));
}

DEV float tsum16(f32x16 v) {
  float a = (v[0] + v[1]) + (v[2] + v[3]);
  float b = (v[4] + v[5]) + (v[6] + v[7]);
  float c = (v[8] + v[9]) + (v[10] + v[11]);
  float d = (v[12] + v[13]) + (v[14] + v[15]);
  return (a + b) + (c + d);
}

// ============ 1) fp32 -> bf16 convert (x, qkv_w, proj_w) ============
__global__ __launch_bounds__(256) void convert_k(
    const float* __restrict__ x, const float* __restrict__ wq,
    const float* __restrict__ wp, u16* __restrict__ xb, u16* __restrict__ wqb,
    u16* __restrict__ wpb) {
  const int NX = 1048576, NQ = 786432, NP = 262144;  // float4 counts
  const int tot = NX + NQ + NP;
  int idx = blockIdx.x * blockDim.x + threadIdx.x;
  int stride = gridDim.x * blockDim.x;
  for (; idx < tot; idx += stride) {
    int i = idx;
    const float* s;
    u16* d;
    if (i < NX) {
      s = x; d = xb;
    } else if (i < NX + NQ) {
      i -= NX; s = wq; d = wqb;
    } else {
      i -= NX + NQ; s = wp; d = wpb;
    }
    float4 v = ((const float4*)s)[i];
    ushort4 o;
    o.x = f2bf(v.x); o.y = f2bf(v.y); o.z = f2bf(v.z); o.w = f2bf(v.w);
    ((ushort4*)d)[i] = o;
  }
}

// ============ 2/4) C = A[M,K] * B[N,K]^T, 128x128 tile, 4 waves ============
template <int EPI>
__global__ __launch_bounds__(256) void gemm_bt(
    const u16* __restrict__ A, const u16* __restrict__ B, int K,
    u16* __restrict__ qbuf, u16* __restrict__ kbuf, u16* __restrict__ vtbuf,
    float* __restrict__ outp, const float* __restrict__ bias) {
  constexpr int TRN = (EPI == 0) ? 128 * 136 : 8192;
  __shared__ union alignas(16) SM {
    u16 ab[8192];       // A tile [128][32] + B tile [128][32]
    u16 tr[TRN];        // v-transpose buffer, stride 136
  } sm;
  const int tid = threadIdx.x;
  const int l = tid & 63, w = tid >> 6, g = l >> 4, r = l & 15;
  const int bm = blockIdx.x, bn = blockIdx.y;
  const int wr = w >> 1, wc = w & 1;
  f32x4 acc[4][4] = {};
  const u16* Ab = A + (size_t)bm * 128 * K;
  const u16* Bb = B + (size_t)bn * 128 * K;
  char* sA = (char*)sm.ab;
  char* sB = sA + 8192;
  const int kit = K >> 5;
  for (int kt = 0; kt < kit; ++kt) {
    const int k0 = kt << 5;
#pragma unroll
    for (int i = 0; i < 2; ++i) {
      int c = i * 256 + tid;
      int row = c >> 2, sl = c & 3;
      gload16(Ab + row * K + k0 + sl * 8, sA + (i * 256 + w * 64) * 16);
      gload16(Bb + row * K + k0 + sl * 8, sB + (i * 256 + w * 64) * 16);
    }
    __syncthreads();
    bf16x8 af[4], bf[4];
#pragma unroll
    for (int mb = 0; mb < 4; ++mb)
      af[mb] = *(const bf16x8*)(sA + (wr * 64 + mb * 16 + r) * 64 + g * 16);
#pragma unroll
    for (int nb = 0; nb < 4; ++nb)
      bf[nb] = *(const bf16x8*)(sB + (wc * 64 + nb * 16 + r) * 64 + g * 16);
#pragma unroll
    for (int mb = 0; mb < 4; ++mb)
#pragma unroll
      for (int nb = 0; nb < 4; ++nb)
        acc[mb][nb] = __builtin_amdgcn_mfma_f32_16x16x32_bf16(
            af[mb], bf[nb], acc[mb][nb], 0, 0, 0);
    __syncthreads();
  }
  const int m0 = bm * 128 + wr * 64;
  if (EPI == 1) {
#pragma unroll
    for (int nb = 0; nb < 4; ++nb) {
      int o = bn * 128 + wc * 64 + nb * 16 + r;
      float bi = bias[o];
#pragma unroll
      for (int mb = 0; mb < 4; ++mb)
#pragma unroll
        for (int j = 0; j < 4; ++j) {
          int m = m0 + mb * 16 + g * 4 + j;
          outp[(size_t)m * 1024 + o] = acc[mb][nb][j] + bi;
        }
    }
  } else {
    const int o0 = bn * 128;
    if (o0 < 2048) {
      u16* dst = (o0 < 1024) ? qbuf : kbuf;
      const float qs = (o0 < 1024) ? 0.18033688011112042f : 1.0f;
#pragma unroll
      for (int nb = 0; nb < 4; ++nb) {
        int o = o0 + wc * 64 + nb * 16 + r;
        int h = (o >> 6) & 15, d = o & 63;
#pragma unroll
        for (int mb = 0; mb < 4; ++mb)
#pragma unroll
          for (int j = 0; j < 4; ++j) {
            int m = m0 + mb * 16 + g * 4 + j;
            int b = m >> 11, n = m & 2047;
            dst[(size_t)(((b << 4) + h) * 2048 + n) * 64 + d] =
                f2bf(acc[mb][nb][j] * qs);
          }
      }
    } else {
      // v block: transpose 128(m) x 128(o) tile via LDS, write [B,H,D,N]
#pragma unroll
      for (int nb = 0; nb < 4; ++nb) {
        int ol = wc * 64 + nb * 16 + r;
#pragma unroll
        for (int mb = 0; mb < 4; ++mb)
#pragma unroll
          for (int j = 0; j < 4; ++j) {
            int ml = wr * 64 + mb * 16 + g * 4 + j;
            sm.tr[ol * 136 + ml] = f2bf(acc[mb][nb][j]);
          }
      }
      __syncthreads();
      const int b = bm >> 4;
      const int n0 = (bm & 15) * 128;
#pragma unroll
      for (int i = 0; i < 8; ++i) {
        int c = i * 256 + tid;
        int ro = c >> 4, ms = c & 15;
        int o = o0 + ro;
        int h = (o >> 6) & 15, d = o & 63;
        bf16x8 v = *(const bf16x8*)(sm.tr + ro * 136 + ms * 8);
        *(bf16x8*)(vtbuf + (size_t)(((b << 4) + h) * 64 + d) * 2048 + n0 +
                   ms * 8) = v;
      }
    }
  }
}

// ============ 3) flash attention, 32x32x16 MFMA, in-register P ============
// 4 waves x 32 q-rows. K/V 64x64 tiles, 4-deep LDS ring (XOR-swizzled rows),
// staged 2 tiles ahead via global_load_lds; barrier waits vmcnt(4), never 0.
// S^T = mfma(K,Q): lane(hi, q=l&31) reg j holds k16 = (j&3)+8*(j>>2)+4*hi
// per 16-k block (verified C/D layout). Softmax in-register; cross-half
// reduce via __shfl_xor(,32). P-fragments built to match the SAME operand
// k-mapping assumption used for the V-side LDS loads (Pfrag[hi][e]=P[8hi+e]),
// so any true hardware operand permutation cancels between the two sides:
//   own words P0=k{0,1}/P1=k{2,3} (hi=0) or k{4,5}/k{6,7} (hi=1),
//   P2,P3 likewise at +8; exchange with partner lane via shfl_xor(,32):
//   u.x = hi?P2s:P0, u.y = hi?P3s:P1, u.z = hi?P2:P0s, u.w = hi?P3:P1s.
// PV deferred one iter so its MFMAs overlap softmax VALU.
__global__ __launch_bounds__(256, 2) void attn_k(
    const u16* __restrict__ qbuf, const u16* __restrict__ kbuf,
    const u16* __restrict__ vtbuf, u16* __restrict__ hbuf) {
  __shared__ alignas(16) char sKV[65536];  // K ring @0, V ring @32768
  const int tid = threadIdx.x;
  const int l = tid & 63, w = tid >> 6;
  const int hi = l >> 5, q31 = l & 31;
  const int sw = (l & 7) << 4;
  const int id = blockIdx.x;
  const int swz = (id & 7) * 64 + (id >> 3);  // XCD-grouped
  const int bh = swz >> 4;
  const int q0 = (swz & 15) * 128 + w * 32;
  const u16* Qb = qbuf + ((size_t)bh * 2048 + q0) * 64;
  const u16* Kb = kbuf + (size_t)bh * 2048 * 64;
  const u16* Vb = vtbuf + (size_t)bh * 64 * 2048;
  // Q fragments (B-operand): col q=q31, d = 16c + 8*hi + e
  bf16x8 qf[4];
#pragma unroll
  for (int c = 0; c < 4; ++c)
    qf[c] = *(const bf16x8*)(Qb + q31 * 64 + c * 16 + hi * 8);
  f32x16 acc[2] = {};
  bf16x8 pf[4];
  float mrun = -3e38f, lrun = 0.f;
  const int rowb = q31 * 128;
  int roff[4];
#pragma unroll
  for (int c = 0; c < 4; ++c) roff[c] = (c * 32 + hi * 16) ^ sw;

  auto stage = [&](int t) {
    const int buf = (t & 3) * 8192;
    const int k0 = t * 64;
#pragma unroll
    for (int i = 0; i < 2; ++i) {
      int c = i * 256 + tid;
      int row = c >> 3, sl = c & 7;
      gload16(Kb + (k0 + row) * 64 + ((sl ^ (row & 7)) * 8),
              sKV + buf + (i * 256 + w * 64) * 16);
      gload16(Vb + (size_t)row * 2048 + k0 + ((sl ^ (row & 7)) * 8),
              sKV + 32768 + buf + (i * 256 + w * 64) * 16);
    }
  };

  stage(0);
  stage(1);
  for (int t = 0; t < 32; ++t) {
    if (t < 31)
      asm volatile("s_waitcnt vmcnt(4)" ::: "memory");
    else
      asm volatile("s_waitcnt vmcnt(0)" ::: "memory");
    __builtin_amdgcn_s_barrier();
    asm volatile("" ::: "memory");
    // K fragments for tile t
    const char* kb_ = sKV + (t & 3) * 8192 + rowb;
    bf16x8 kf[2][4];
#pragma unroll
    for (int kt = 0; kt < 2; ++kt)
#pragma unroll
      for (int c = 0; c < 4; ++c)
        kf[kt][c] = *(const bf16x8*)(kb_ + kt * 4096 + roff[c]);
    if (t < 30) stage(t + 2);
    // S^T = K * Q^T
    f32x16 stv[2];
    __builtin_amdgcn_s_setprio(1);
#pragma unroll
    for (int kt = 0; kt < 2; ++kt) {
      f32x16 z = {};
#pragma unroll
      for (int c = 0; c < 4; ++c)
        z = __builtin_amdgcn_mfma_f32_32x32x16_bf16(kf[kt][c], qf[c], z, 0, 0, 0);
      stv[kt] = z;
    }
    __builtin_amdgcn_s_setprio(0);
    // PV for tile t-1 (overlaps softmax below in the MFMA pipe)
    if (t > 0) {
      const char* vb_ = sKV + 32768 + ((t - 1) & 3) * 8192 + rowb;
      bf16x8 vf[2][4];
#pragma unroll
      for (int dt = 0; dt < 2; ++dt)
#pragma unroll
        for (int ks = 0; ks < 4; ++ks)
          vf[dt][ks] = *(const bf16x8*)(vb_ + dt * 4096 + roff[ks]);
      __builtin_amdgcn_s_setprio(1);
#pragma unroll
      for (int dt = 0; dt < 2; ++dt)
#pragma unroll
        for (int ks = 0; ks < 4; ++ks)
          acc[dt] = __builtin_amdgcn_mfma_f32_32x32x16_bf16(vf[dt][ks], pf[ks],
                                                            acc[dt], 0, 0, 0);
      __builtin_amdgcn_s_setprio(0);
    }
    // online softmax (lane owns column q; halves hold disjoint k)
    float mx = fmaxf(tmax16(stv[0]), tmax16(stv[1]));
    mx = fmaxf(mx, __shfl_xor(mx, 32));
    if (__any(mx > mrun + 8.0f)) {  // defer-rescale (exp2 units)
      float mn = fmaxf(mrun, mx);
      float corr = exp2f(mrun - mn);
      lrun *= corr;
      acc[0] *= corr;
      acc[1] *= corr;
      mrun = mn;
    }
#pragma unroll
    for (int kt = 0; kt < 2; ++kt)
#pragma unroll
      for (int j = 0; j < 16; ++j) stv[kt][j] = exp2f(stv[kt][j] - mrun);
    float ps = tsum16(stv[0]) + tsum16(stv[1]);
    ps += __shfl_xor(ps, 32);
    lrun += ps;
    // pack P -> PV B-fragments (cvt_pk + shfl_xor(32) + select, no LDS)
#pragma unroll
    for (int ks = 0; ks < 4; ++ks) {
      const f32x16& sv = stv[ks >> 1];
      const int b0 = (ks & 1) * 8;
      u32 P0 = cvtpk(sv[b0 + 0], sv[b0 + 1]);
      u32 P1 = cvtpk(sv[b0 + 2], sv[b0 + 3]);
      u32 P2 = cvtpk(sv[b0 + 4], sv[b0 + 5]);
      u32 P3 = cvtpk(sv[b0 + 6], sv[b0 + 7]);
      u32 P0s = __shfl_xor(P0, 32);
      u32 P1s = __shfl_xor(P1, 32);
      u32 P2s = __shfl_xor(P2, 32);
      u32 P3s = __shfl_xor(P3, 32);
      uint4 u;
      u.x = hi ? P2s : P0;
      u.y = hi ? P3s : P1;
      u.z = hi ? P2 : P0s;
      u.w = hi ? P3 : P1s;
      pf[ks] = __builtin_bit_cast(bf16x8, u);
    }
  }
  // tail: PV for tile 31
  {
    const char* vb_ = sKV + 32768 + (31 & 3) * 8192 + rowb;
    bf16x8 vf[2][4];
#pragma unroll
    for (int dt = 0; dt < 2; ++dt)
#pragma unroll
      for (int ks = 0; ks < 4; ++ks)
        vf[dt][ks] = *(const bf16x8*)(vb_ + dt * 4096 + roff[ks]);
#pragma unroll
    for (int dt = 0; dt < 2; ++dt)
#pragma unroll
      for (int ks = 0; ks < 4; ++ks)
        acc[dt] = __builtin_amdgcn_mfma_f32_32x32x16_bf16(vf[dt][ks], pf[ks],
                                                          acc[dt], 0, 0, 0);
  }
  // epilogue: lane holds q = q0+q31; d = dt*32 + 8*rg + 4*hi + j
  const int b = bh >> 4, h = bh & 15;
  const float inv = 1.0f / lrun;
  u16* orow = hbuf + ((size_t)(b * 2048 + q0 + q31)) * 1024 + h * 64;
#pragma unroll
  for (int dt = 0; dt < 2; ++dt)
#pragma unroll
    for (int rg = 0; rg < 4; ++rg) {
      uint2 pk;
      pk.x = cvtpk(acc[dt][4 * rg + 0] * inv, acc[dt][4 * rg + 1] * inv);
      pk.y = cvtpk(acc[dt][4 * rg + 2] * inv, acc[dt][4 * rg + 3] * inv);
      *(uint2*)(orow + dt * 32 + rg * 8 + hi * 4) = pk;
    }
}

extern "C" void kernel_launch(void* const* d_in, const int* in_sizes, int n_in,
                              void* d_out, int out_size, void* d_ws,
                              size_t ws_size, hipStream_t stream) {
  const float* x = (const float*)d_in[0];
  const float* qkv_w = (const float*)d_in[1];
  const float* proj_w = (const float*)d_in[2];
  const float* proj_b = (const float*)d_in[3];
  float* out = (float*)d_out;
  char* ws = (char*)d_ws;
  if (ws_size < 50331648) return;  // need 48 MiB of scratch
  u16* xb  = (u16*)(ws + 0);         // [4096][1024] bf16
  u16* wqb = (u16*)(ws + 8388608);   // [3072][1024] bf16
  u16* wpb = (u16*)(ws + 14680064);  // [1024][1024] bf16
  u16* qb  = (u16*)(ws + 16777216);  // [B,H,N,D] bf16 (pre-scaled)
  u16* kb  = (u16*)(ws + 25165824);  // [B,H,N,D] bf16
  u16* vtb = (u16*)(ws + 33554432);  // [B,H,D,N] bf16
  u16* hb  = (u16*)(ws + 41943040);  // [B*N][C] bf16
  convert_k<<<dim3(2048), dim3(256), 0, stream>>>(x, qkv_w, proj_w, xb, wqb, wpb);
  gemm_bt<0><<<dim3(32, 24), dim3(256), 0, stream>>>(
      xb, wqb, 1024, qb, kb, vtb, nullptr, nullptr);
  attn_k<<<dim3(512), dim3(256), 0, stream>>>(qb, kb, vtb, hb);
  gemm_bt<1><<<dim3(32, 8), dim3(256), 0, stream>>>(
      hb, wpb, 1024, nullptr, nullptr, nullptr, out, proj_b);
}

// Round 6
// 140.827 us; speedup vs baseline: 1.7492x; 1.0428x over previous
//
#include <hip/hip_runtime.h>
#include <stdint.h>

typedef __bf16 bf16x8 __attribute__((ext_vector_type(8)));
typedef float f32x4 __attribute__((ext_vector_type(4)));
typedef float f32x16 __attribute__((ext_vector_type(16)));
typedef uint16_t u16;
typedef uint32_t u32;
typedef uint32_t gu32 __attribute__((address_space(1)));
typedef uint32_t lu32 __attribute__((address_space(3)));

#define DEV static __device__ __forceinline__

DEV u16 f2bf(float f) {
  u32 u = __builtin_bit_cast(u32, f);
  return (u16)((u + 0x8000u) >> 16);
}

DEV u32 cvtpk(float lo, float hi) {
  u32 r;
  asm("v_cvt_pk_bf16_f32 %0, %1, %2" : "=v"(r) : "v"(lo), "v"(hi));
  return r;
}

DEV void gload16(const void* g, void* l) {
  __builtin_amdgcn_global_load_lds((gu32*)(uintptr_t)g, (lu32*)(uintptr_t)l,
                                   16, 0, 0);
}

DEV float tmax16(f32x16 v) {
  float a = fmaxf(fmaxf(v[0], v[1]), fmaxf(v[2], v[3]));
  float b = fmaxf(fmaxf(v[4], v[5]), fmaxf(v[6], v[7]));
  float c = fmaxf(fmaxf(v[8], v[9]), fmaxf(v[10], v[11]));
  float d = fmaxf(fmaxf(v[12], v[13]), fmaxf(v[14], v[15]));
  return fmaxf(fmaxf(a, b), fmaxf(c, d));
}

DEV float tsum16(f32x16 v) {
  float a = (v[0] + v[1]) + (v[2] + v[3]);
  float b = (v[4] + v[5]) + (v[6] + v[7]);
  float c = (v[8] + v[9]) + (v[10] + v[11]);
  float d = (v[12] + v[13]) + (v[14] + v[15]);
  return (a + b) + (c + d);
}

// ============ 1) fp32 -> bf16 convert (x, qkv_w, proj_w) ============
__global__ __launch_bounds__(256) void convert_k(
    const float* __restrict__ x, const float* __restrict__ wq,
    const float* __restrict__ wp, u16* __restrict__ xb, u16* __restrict__ wqb,
    u16* __restrict__ wpb) {
  const int NX = 1048576, NQ = 786432, NP = 262144;  // float4 counts
  const int tot = NX + NQ + NP;
  int idx = blockIdx.x * blockDim.x + threadIdx.x;
  int stride = gridDim.x * blockDim.x;
  for (; idx < tot; idx += stride) {
    int i = idx;
    const float* s;
    u16* d;
    if (i < NX) {
      s = x; d = xb;
    } else if (i < NX + NQ) {
      i -= NX; s = wq; d = wqb;
    } else {
      i -= NX + NQ; s = wp; d = wpb;
    }
    float4 v = ((const float4*)s)[i];
    ushort4 o;
    o.x = f2bf(v.x); o.y = f2bf(v.y); o.z = f2bf(v.z); o.w = f2bf(v.w);
    ((ushort4*)d)[i] = o;
  }
}

// ============ 2/4) C = A[M,K] * B[N,K]^T, 128x128 tile, 4 waves ============
template <int EPI>
__global__ __launch_bounds__(256) void gemm_bt(
    const u16* __restrict__ A, const u16* __restrict__ B, int K,
    u16* __restrict__ qbuf, u16* __restrict__ kbuf, u16* __restrict__ vtbuf,
    float* __restrict__ outp, const float* __restrict__ bias) {
  constexpr int TRN = (EPI == 0) ? 128 * 136 : 8192;
  __shared__ union alignas(16) SM {
    u16 ab[8192];       // A tile [128][32] + B tile [128][32]
    u16 tr[TRN];        // v-transpose buffer, stride 136
  } sm;
  const int tid = threadIdx.x;
  const int l = tid & 63, w = tid >> 6, g = l >> 4, r = l & 15;
  const int bm = blockIdx.x, bn = blockIdx.y;
  const int wr = w >> 1, wc = w & 1;
  f32x4 acc[4][4] = {};
  const u16* Ab = A + (size_t)bm * 128 * K;
  const u16* Bb = B + (size_t)bn * 128 * K;
  char* sA = (char*)sm.ab;
  char* sB = sA + 8192;
  const int kit = K >> 5;
  for (int kt = 0; kt < kit; ++kt) {
    const int k0 = kt << 5;
#pragma unroll
    for (int i = 0; i < 2; ++i) {
      int c = i * 256 + tid;
      int row = c >> 2, sl = c & 3;
      gload16(Ab + row * K + k0 + sl * 8, sA + (i * 256 + w * 64) * 16);
      gload16(Bb + row * K + k0 + sl * 8, sB + (i * 256 + w * 64) * 16);
    }
    __syncthreads();
    bf16x8 af[4], bf[4];
#pragma unroll
    for (int mb = 0; mb < 4; ++mb)
      af[mb] = *(const bf16x8*)(sA + (wr * 64 + mb * 16 + r) * 64 + g * 16);
#pragma unroll
    for (int nb = 0; nb < 4; ++nb)
      bf[nb] = *(const bf16x8*)(sB + (wc * 64 + nb * 16 + r) * 64 + g * 16);
#pragma unroll
    for (int mb = 0; mb < 4; ++mb)
#pragma unroll
      for (int nb = 0; nb < 4; ++nb)
        acc[mb][nb] = __builtin_amdgcn_mfma_f32_16x16x32_bf16(
            af[mb], bf[nb], acc[mb][nb], 0, 0, 0);
    __syncthreads();
  }
  const int m0 = bm * 128 + wr * 64;
  if (EPI == 1) {
#pragma unroll
    for (int nb = 0; nb < 4; ++nb) {
      int o = bn * 128 + wc * 64 + nb * 16 + r;
      float bi = bias[o];
#pragma unroll
      for (int mb = 0; mb < 4; ++mb)
#pragma unroll
        for (int j = 0; j < 4; ++j) {
          int m = m0 + mb * 16 + g * 4 + j;
          outp[(size_t)m * 1024 + o] = acc[mb][nb][j] + bi;
        }
    }
  } else {
    const int o0 = bn * 128;
    if (o0 < 2048) {
      u16* dst = (o0 < 1024) ? qbuf : kbuf;
      const float qs = (o0 < 1024) ? 0.18033688011112042f : 1.0f;
#pragma unroll
      for (int nb = 0; nb < 4; ++nb) {
        int o = o0 + wc * 64 + nb * 16 + r;
        int h = (o >> 6) & 15, d = o & 63;
#pragma unroll
        for (int mb = 0; mb < 4; ++mb)
#pragma unroll
          for (int j = 0; j < 4; ++j) {
            int m = m0 + mb * 16 + g * 4 + j;
            int b = m >> 11, n = m & 2047;
            dst[(size_t)(((b << 4) + h) * 2048 + n) * 64 + d] =
                f2bf(acc[mb][nb][j] * qs);
          }
      }
    } else {
      // v block: transpose 128(m) x 128(o) tile via LDS, write [B,H,D,N]
#pragma unroll
      for (int nb = 0; nb < 4; ++nb) {
        int ol = wc * 64 + nb * 16 + r;
#pragma unroll
        for (int mb = 0; mb < 4; ++mb)
#pragma unroll
          for (int j = 0; j < 4; ++j) {
            int ml = wr * 64 + mb * 16 + g * 4 + j;
            sm.tr[ol * 136 + ml] = f2bf(acc[mb][nb][j]);
          }
      }
      __syncthreads();
      const int b = bm >> 4;
      const int n0 = (bm & 15) * 128;
#pragma unroll
      for (int i = 0; i < 8; ++i) {
        int c = i * 256 + tid;
        int ro = c >> 4, ms = c & 15;
        int o = o0 + ro;
        int h = (o >> 6) & 15, d = o & 63;
        bf16x8 v = *(const bf16x8*)(sm.tr + ro * 136 + ms * 8);
        *(bf16x8*)(vtbuf + (size_t)(((b << 4) + h) * 64 + d) * 2048 + n0 +
                   ms * 8) = v;
      }
    }
  }
}

// ============ 3) flash attention, k-split x2, 8 waves, in-register P ======
// Block: 128 q, 8 waves. Waves 0-3 handle k in [0,1024), waves 4-7 handle
// [1024,2048) -> 16 iters each, 2x total waves (16/CU) vs the q-only split.
// Per half: K/V 64x64 tiles, 2-deep LDS rings (XOR-swizzled rows), staged
// 1 tile ahead via global_load_lds; top-of-iter waits own vmcnt(0) (loads
// were issued a full iter earlier). S^T = mfma(K,Q), softmax in-register
// (cross-half reduce via shfl_xor(32)), P packed to PV B-fragments via
// cvt_pk + shfl_xor(32) + select (k-mapping consistent with V-side loads,
// so any true HW operand permutation cancels). Final: upper waves publish
// (O,m,l) partials through LDS; lower waves do the exact online-softmax
// merge and write h.
__global__ __launch_bounds__(512, 4) void attn_k(
    const u16* __restrict__ qbuf, const u16* __restrict__ kbuf,
    const u16* __restrict__ vtbuf, u16* __restrict__ hbuf) {
  __shared__ alignas(16) char sKV[65536];  // K rings @0 (32KB), V @32768
  const int tid = threadIdx.x;
  const int l = tid & 63, w = tid >> 6;  // w 0..7
  const int s = w >> 2;                  // k-half
  const int hi = l >> 5, q31 = l & 31;
  const int sw = (l & 7) << 4;
  const int id = blockIdx.x;
  const int swz = (id & 7) * 64 + (id >> 3);  // XCD-grouped
  const int bh = swz >> 4;
  const int q0 = (swz & 15) * 128 + (w & 3) * 32;
  const u16* Qb = qbuf + ((size_t)bh * 2048 + q0) * 64;
  const u16* Kb = kbuf + (size_t)bh * 2048 * 64 + (size_t)s * 1024 * 64;
  const u16* Vb = vtbuf + (size_t)bh * 64 * 2048 + s * 1024;
  char* sK = sKV + s * 16384;
  char* sV = sKV + 32768 + s * 16384;
  // Q fragments (B-operand): col q=q31, d = 16c + 8*hi + e
  bf16x8 qf[4];
#pragma unroll
  for (int c = 0; c < 4; ++c)
    qf[c] = *(const bf16x8*)(Qb + q31 * 64 + c * 16 + hi * 8);
  f32x16 acc[2] = {};
  float mrun = -3e38f, lrun = 0.f;
  const int rowb = q31 * 128;
  int roff[4];
#pragma unroll
  for (int c = 0; c < 4; ++c) roff[c] = (c * 32 + hi * 16) ^ sw;

  auto stage = [&](int t) {
    const int buf = (t & 1) * 8192;
    const int k0 = t * 64;
    const int ltid = tid & 255;
#pragma unroll
    for (int i = 0; i < 2; ++i) {
      int c = i * 256 + ltid;
      int row = c >> 3, sl = c & 7;
      gload16(Kb + (k0 + row) * 64 + ((sl ^ (row & 7)) * 8),
              sK + buf + (i * 256 + (w & 3) * 64) * 16);
      gload16(Vb + (size_t)row * 2048 + k0 + ((sl ^ (row & 7)) * 8),
              sV + buf + (i * 256 + (w & 3) * 64) * 16);
    }
  };

  stage(0);
  for (int t = 0; t < 16; ++t) {
    asm volatile("s_waitcnt vmcnt(0)" ::: "memory");
    __builtin_amdgcn_s_barrier();
    asm volatile("" ::: "memory");
    const char* kb_ = sK + (t & 1) * 8192 + rowb;
    const char* vb_ = sV + (t & 1) * 8192 + rowb;
    // K fragments for tile t
    bf16x8 kf[2][4];
#pragma unroll
    for (int kt = 0; kt < 2; ++kt)
#pragma unroll
      for (int c = 0; c < 4; ++c)
        kf[kt][c] = *(const bf16x8*)(kb_ + kt * 4096 + roff[c]);
    if (t < 15) stage(t + 1);
    // S^T = K * Q^T
    f32x16 stv[2];
#pragma unroll
    for (int kt = 0; kt < 2; ++kt) {
      f32x16 z = {};
#pragma unroll
      for (int c = 0; c < 4; ++c)
        z = __builtin_amdgcn_mfma_f32_32x32x16_bf16(kf[kt][c], qf[c], z, 0, 0, 0);
      stv[kt] = z;
    }
    // V^T fragments
    bf16x8 vf[2][4];
#pragma unroll
    for (int dt = 0; dt < 2; ++dt)
#pragma unroll
      for (int ks = 0; ks < 4; ++ks)
        vf[dt][ks] = *(const bf16x8*)(vb_ + dt * 4096 + roff[ks]);
    // online softmax (lane owns column q; halves hold disjoint k)
    float mx = fmaxf(tmax16(stv[0]), tmax16(stv[1]));
    mx = fmaxf(mx, __shfl_xor(mx, 32));
    if (__any(mx > mrun + 8.0f)) {  // defer-rescale (exp2 units)
      float mn = fmaxf(mrun, mx);
      float corr = __builtin_amdgcn_exp2f(mrun - mn);
      lrun *= corr;
      acc[0] *= corr;
      acc[1] *= corr;
      mrun = mn;
    }
#pragma unroll
    for (int kt = 0; kt < 2; ++kt)
#pragma unroll
      for (int j = 0; j < 16; ++j)
        stv[kt][j] = __builtin_amdgcn_exp2f(stv[kt][j] - mrun);
    float ps = tsum16(stv[0]) + tsum16(stv[1]);
    ps += __shfl_xor(ps, 32);
    lrun += ps;
    // pack P -> PV B-fragments (cvt_pk + shfl_xor(32) + select, no LDS)
    bf16x8 pf[4];
#pragma unroll
    for (int ks = 0; ks < 4; ++ks) {
      const f32x16& sv = stv[ks >> 1];
      const int b0 = (ks & 1) * 8;
      u32 P0 = cvtpk(sv[b0 + 0], sv[b0 + 1]);
      u32 P1 = cvtpk(sv[b0 + 2], sv[b0 + 3]);
      u32 P2 = cvtpk(sv[b0 + 4], sv[b0 + 5]);
      u32 P3 = cvtpk(sv[b0 + 6], sv[b0 + 7]);
      u32 P0s = __shfl_xor(P0, 32);
      u32 P1s = __shfl_xor(P1, 32);
      u32 P2s = __shfl_xor(P2, 32);
      u32 P3s = __shfl_xor(P3, 32);
      uint4 u;
      u.x = hi ? P2s : P0;
      u.y = hi ? P3s : P1;
      u.z = hi ? P2 : P0s;
      u.w = hi ? P3 : P1s;
      pf[ks] = __builtin_bit_cast(bf16x8, u);
    }
    // O^T += V^T * P^T
#pragma unroll
    for (int dt = 0; dt < 2; ++dt)
#pragma unroll
      for (int ks = 0; ks < 4; ++ks)
        acc[dt] = __builtin_amdgcn_mfma_f32_32x32x16_bf16(vf[dt][ks], pf[ks],
                                                          acc[dt], 0, 0, 0);
  }
  // ================= in-block merge of the two k-halves =================
  __syncthreads();
  if (s == 1) {
    // publish partials: O as f32 [32 q][68 pad] + (m,l)
    float* po = (float*)(sKV + (size_t)(w & 3) * 8704);
#pragma unroll
    for (int dt = 0; dt < 2; ++dt)
#pragma unroll
      for (int rg = 0; rg < 4; ++rg) {
        int d0 = dt * 32 + rg * 8 + hi * 4;
        f32x4 v;
        v[0] = acc[dt][4 * rg + 0];
        v[1] = acc[dt][4 * rg + 1];
        v[2] = acc[dt][4 * rg + 2];
        v[3] = acc[dt][4 * rg + 3];
        *(f32x4*)(po + q31 * 68 + d0) = v;
      }
    if (hi == 0) {
      float2* pml = (float2*)(sKV + 34816 + (w & 3) * 256);
      pml[q31] = make_float2(mrun, lrun);
    }
  }
  __syncthreads();
  if (s == 0) {
    const float* po = (const float*)(sKV + (size_t)w * 8704);
    const float2* pml = (const float2*)(sKV + 34816 + w * 256);
    float2 ml2 = pml[q31];
    float m = fmaxf(mrun, ml2.x);
    float a = __builtin_amdgcn_exp2f(mrun - m);
    float b2 = __builtin_amdgcn_exp2f(ml2.x - m);
    float inv = 1.0f / (lrun * a + ml2.y * b2);
    const int b = bh >> 4, h = bh & 15;
    u16* orow = hbuf + ((size_t)(b * 2048 + q0 + q31)) * 1024 + h * 64;
#pragma unroll
    for (int dt = 0; dt < 2; ++dt)
#pragma unroll
      for (int rg = 0; rg < 4; ++rg) {
        int d0 = dt * 32 + rg * 8 + hi * 4;
        f32x4 p2 = *(const f32x4*)(po + q31 * 68 + d0);
        float v0 = (acc[dt][4 * rg + 0] * a + p2[0] * b2) * inv;
        float v1 = (acc[dt][4 * rg + 1] * a + p2[1] * b2) * inv;
        float v2 = (acc[dt][4 * rg + 2] * a + p2[2] * b2) * inv;
        float v3 = (acc[dt][4 * rg + 3] * a + p2[3] * b2) * inv;
        uint2 pk;
        pk.x = cvtpk(v0, v1);
        pk.y = cvtpk(v2, v3);
        *(uint2*)(orow + d0) = pk;
      }
  }
}

extern "C" void kernel_launch(void* const* d_in, const int* in_sizes, int n_in,
                              void* d_out, int out_size, void* d_ws,
                              size_t ws_size, hipStream_t stream) {
  const float* x = (const float*)d_in[0];
  const float* qkv_w = (const float*)d_in[1];
  const float* proj_w = (const float*)d_in[2];
  const float* proj_b = (const float*)d_in[3];
  float* out = (float*)d_out;
  char* ws = (char*)d_ws;
  if (ws_size < 50331648) return;  // need 48 MiB of scratch
  u16* xb  = (u16*)(ws + 0);         // [4096][1024] bf16
  u16* wqb = (u16*)(ws + 8388608);   // [3072][1024] bf16
  u16* wpb = (u16*)(ws + 14680064);  // [1024][1024] bf16
  u16* qb  = (u16*)(ws + 16777216);  // [B,H,N,D] bf16 (pre-scaled)
  u16* kb  = (u16*)(ws + 25165824);  // [B,H,N,D] bf16
  u16* vtb = (u16*)(ws + 33554432);  // [B,H,D,N] bf16
  u16* hb  = (u16*)(ws + 41943040);  // [B*N][C] bf16
  convert_k<<<dim3(2048), dim3(256), 0, stream>>>(x, qkv_w, proj_w, xb, wqb, wpb);
  gemm_bt<0><<<dim3(32, 24), dim3(256), 0, stream>>>(
      xb, wqb, 1024, qb, kb, vtb, nullptr, nullptr);
  attn_k<<<dim3(512), dim3(512), 0, stream>>>(qb, kb, vtb, hb);
  gemm_bt<1><<<dim3(32, 8), dim3(256), 0, stream>>>(
      hb, wpb, 1024, nullptr, nullptr, nullptr, out, proj_b);
}